// Round 9
// baseline (58.106 us; speedup 1.0000x reference)
//
#include <hip/hip_runtime.h>
#include <hip/hip_bf16.h>

// SINDy: theta(N,969) @ (C*mask)(969,16), plus l1 = mean|C*mask|.
// N=262144, latent=16, lib = 969; K padded to 992 = 31*32.
//
// Rotation design (R5): lane l (slice g=l>>4) computes the g-th orbit member
// of each of 248 orbit reps as compile-time-indexed products of its ROTATED z.
// Coefficients gathered to match by prep.
//
// R8/R9:
//  (1) fp16 instead of bf16: A-frag packed with __builtin_amdgcn_cvt_pkrtz
//      (single v_cvt_pkrtz_f16_f32) -> mfma_f32_16x16x32_f16. fp16 is MORE
//      accurate here (|th| <= ~150 << 65504; 10 mantissa bits vs 7).
//  (2) 4x fewer, longer waves: 1024 blocks, each wave loops 4 tiles with
//      z prefetch; B-table in LDS once per block (amortized).
//  (3) prep computes L1 loss in a dedicated block -> no memset, no atomics.
//  R9: fix cvt_pkrtz return type (__fp16 vector) via bit_cast assembly.

#define LIB    969
#define NSLOT  248
#define NCHUNK 31
#define NROWS  262144
#define NOUT   16
#define BTAB_U4 1984   // 31744 B / 16
#define TPW    4       // tiles per wave
#define NBLK   1024    // blocks; 4 waves/block; 4096 waves * 4 tiles = 16384 tiles

typedef _Float16 f16x8 __attribute__((ext_vector_type(8)));
typedef __fp16   h16x2 __attribute__((ext_vector_type(2)));
typedef float    f32x4 __attribute__((ext_vector_type(4)));

struct Maps {
  unsigned char a[NSLOT], b[NSLOT], c[NSLOT];  // zrot indices (16 = sentinel 1.0)
  short l[NSLOT][4];                           // library row per slice g, or -1
};

constexpr Maps build_maps() {
  Maps M{};
  int n = 0;
  M.a[n] = 16; M.b[n] = 16; M.c[n] = 16;
  M.l[n][0] = 0; M.l[n][1] = -1; M.l[n][2] = -1; M.l[n][3] = -1; n++;
  for (int a0 = 0; a0 < 4; a0++) {
    M.a[n] = (unsigned char)a0; M.b[n] = 16; M.c[n] = 16;
    for (int g = 0; g < 4; g++) M.l[n][g] = (short)(1 + ((a0 + 4 * g) & 15));
    n++;
  }
  bool pv[16][16] = {};
  for (int i = 0; i < 16; i++)
    for (int j = i; j < 16; j++) {
      if (pv[i][j]) continue;
      M.a[n] = (unsigned char)i; M.b[n] = (unsigned char)j; M.c[n] = 16;
      int mi[4] = {}, mj[4] = {};
      for (int g = 0; g < 4; g++) {
        int x = (i + 4 * g) & 15, y = (j + 4 * g) & 15;
        int lo = x < y ? x : y, hi = x < y ? y : x;
        mi[g] = lo; mj[g] = hi; pv[lo][hi] = true;
      }
      for (int g = 0; g < 4; g++) {
        bool dup = false;
        for (int h = 0; h < g; h++) if (mi[h] == mi[g] && mj[h] == mj[g]) dup = true;
        M.l[n][g] = dup ? (short)-1
                        : (short)(17 + mi[g] * 16 - mi[g] * (mi[g] - 1) / 2 + (mj[g] - mi[g]));
      }
      n++;
    }
  bool tv[16][16][16] = {};
  for (int i = 0; i < 16; i++)
    for (int j = i; j < 16; j++)
      for (int k = j; k < 16; k++) {
        if (tv[i][j][k]) continue;
        M.a[n] = (unsigned char)i; M.b[n] = (unsigned char)j; M.c[n] = (unsigned char)k;
        int ti[4] = {}, tj[4] = {}, tk[4] = {};
        for (int g = 0; g < 4; g++) {
          int x = (i + 4 * g) & 15, y = (j + 4 * g) & 15, w = (k + 4 * g) & 15, t = 0;
          if (x > y) { t = x; x = y; y = t; }
          if (y > w) { t = y; y = w; w = t; }
          if (x > y) { t = x; x = y; y = t; }
          ti[g] = x; tj[g] = y; tk[g] = w; tv[x][y][w] = true;
        }
        for (int g = 0; g < 4; g++) {
          bool dup = false;
          for (int h = 0; h < g; h++)
            if (ti[h] == ti[g] && tj[h] == tj[g] && tk[h] == tk[g]) dup = true;
          if (dup) { M.l[n][g] = -1; continue; }
          int i2 = ti[g], j2 = tj[g], k2 = tk[g];
          int base = 0;
          for (int a2 = 0; a2 < i2; a2++) base += (16 - a2) * (17 - a2) / 2;
          int off = (j2 - i2) * (16 - i2) - (j2 - i2) * (j2 - i2 - 1) / 2 + (k2 - j2);
          M.l[n][g] = (short)(153 + base + off);
        }
        n++;
      }
  for (; n < NSLOT; n++) {
    M.a[n] = 16; M.b[n] = 16; M.c[n] = 16;
    M.l[n][0] = M.l[n][1] = M.l[n][2] = M.l[n][3] = -1;
  }
  return M;
}
constexpr Maps MP = build_maps();

// ---- prep: gather masked coeffs (fp16) into B-frag/slot order; loss block ----
__global__ __launch_bounds__(256) void prep_kernel(const float* __restrict__ C,
                                                   const float* __restrict__ M,
                                                   unsigned short* __restrict__ Cb,
                                                   float* __restrict__ out) {
  if (blockIdx.x < 62) {
    const int idx = blockIdx.x * 256 + threadIdx.x;   // 0 .. 15871 = NSLOT*4*16
    const int s = idx >> 6, g = (idx >> 4) & 3, o = idx & 15;
    const int li = MP.l[s][g];
    float v = 0.f;
    if (li >= 0) v = C[li * 16 + o] * M[li * 16 + o];
    _Float16 h = (_Float16)v;                          // v_cvt_f16_f32 (RNE)
    unsigned short u; __builtin_memcpy(&u, &h, 2);
    Cb[(((s >> 3) * 4 + g) * 16 + o) * 8 + (s & 7)] = u;
  } else {
    // L1 loss = mean |C*M| over 969*16 = 15504 elements, one block
    __shared__ float part[4];
    float t = 0.f;
    for (int i = threadIdx.x; i < LIB * 16; i += 256) t += fabsf(C[i] * M[i]);
    #pragma unroll
    for (int off = 32; off > 0; off >>= 1) t += __shfl_down(t, off);
    if ((threadIdx.x & 63) == 0) part[threadIdx.x >> 6] = t;
    __syncthreads();
    if (threadIdx.x == 0)
      out[NROWS * NOUT] = (part[0] + part[1] + part[2] + part[3]) * (1.0f / 15504.0f);
  }
}

__global__ __launch_bounds__(256, 4) void sindy_kernel(const float* __restrict__ z,
                                                       const unsigned short* __restrict__ Cb,
                                                       float* __restrict__ out) {
  __shared__ uint4 Blds[BTAB_U4];                   // 31744 B coeff table
  // cooperative one-time fill of the B-table
  {
    const uint4* src = (const uint4*)Cb;
    #pragma unroll
    for (int i = 0; i < 8; i++) {
      int e = i * 256 + threadIdx.x;
      if (e < BTAB_U4) Blds[e] = src[e];
    }
  }

  const int lane = threadIdx.x & 63;
  const int g = lane >> 4;                          // k-slice
  const int o = lane & 15;                          // row-in-tile / out col
  const int wid = blockIdx.x * 4 + (threadIdx.x >> 6);
  const bool b0 = (g & 1) != 0, b1 = (g & 2) != 0;
  const char* bbase = (const char*)Blds + lane * 16;  // + c*1024 per chunk

  // prefetch z for first tile (row = tile*16 + o)
  float4 zn[4];
  {
    const float4* z4 = (const float4*)z;
    const int r = wid * TPW * 16 + o;
    #pragma unroll
    for (int c4 = 0; c4 < 4; c4++) zn[c4] = z4[r * 4 + c4];
  }
  __syncthreads();   // B-table ready

  int t = wid * TPW;
  #pragma unroll
  for (int k = 0; k < TPW; ++k, ++t) {
    // unpack current z
    float z17[17];
    #pragma unroll
    for (int c4 = 0; c4 < 4; c4++) {
      z17[c4 * 4 + 0] = zn[c4].x; z17[c4 * 4 + 1] = zn[c4].y;
      z17[c4 * 4 + 2] = zn[c4].z; z17[c4 * 4 + 3] = zn[c4].w;
    }
    z17[16] = 1.0f;
    // prefetch next tile's z (hidden under this tile's compute)
    if (k + 1 < TPW) {
      const float4* z4 = (const float4*)z;
      const int r = (t + 1) * 16 + o;
      #pragma unroll
      for (int c4 = 0; c4 < 4; c4++) zn[c4] = z4[r * 4 + c4];
    }
    // rotate by 4g with two compile-time-indexed cndmask layers
    float t16[16], zr[17];
    #pragma unroll
    for (int m = 0; m < 16; m++) t16[m] = b0 ? z17[(m + 4) & 15] : z17[m];
    #pragma unroll
    for (int m = 0; m < 16; m++) zr[m] = b1 ? t16[(m + 8) & 15] : t16[m];
    zr[16] = 1.0f;

    f32x4 acc4 = {0.f, 0.f, 0.f, 0.f};
    #pragma unroll
    for (int c = 0; c < NCHUNK; c++) {
      float th[8];
      #pragma unroll
      for (int m = 0; m < 8; m++) {
        const int s = c * 8 + m;
        th[m] = (zr[MP.a[s]] * zr[MP.b[s]]) * zr[MP.c[s]];
      }
      uint4 pkw;
      pkw.x = __builtin_bit_cast(unsigned int, __builtin_amdgcn_cvt_pkrtz(th[0], th[1]));
      pkw.y = __builtin_bit_cast(unsigned int, __builtin_amdgcn_cvt_pkrtz(th[2], th[3]));
      pkw.z = __builtin_bit_cast(unsigned int, __builtin_amdgcn_cvt_pkrtz(th[4], th[5]));
      pkw.w = __builtin_bit_cast(unsigned int, __builtin_amdgcn_cvt_pkrtz(th[6], th[7]));
      f16x8 af = __builtin_bit_cast(f16x8, pkw);
      f16x8 bfrag = *(const f16x8*)(bbase + c * 1024);  // ds_read_b128
      acc4 = __builtin_amdgcn_mfma_f32_16x16x32_f16(af, bfrag, acc4, 0, 0, 0);
    }

    // C/D layout: col = lane&15, row = 4*(lane>>4) + reg
    #pragma unroll
    for (int p = 0; p < 4; p++)
      out[(t * 16 + 4 * g + p) * 16 + o] = acc4[p];
  }
}

extern "C" void kernel_launch(void* const* d_in, const int* in_sizes, int n_in,
                              void* d_out, int out_size, void* d_ws, size_t ws_size,
                              hipStream_t stream) {
  const float* z = (const float*)d_in[0];
  const float* C = (const float*)d_in[1];
  const float* M = (const float*)d_in[2];
  float* out = (float*)d_out;
  unsigned short* Cb = (unsigned short*)d_ws;         // 31744 B coeff slots

  prep_kernel<<<63, 256, 0, stream>>>(C, M, Cb, out);
  sindy_kernel<<<NBLK, 256, 0, stream>>>(z, Cb, out);
}